// Round 2
// baseline (1229.651 us; speedup 1.0000x reference)
//
#include <hip/hip_runtime.h>
#include <hip/hip_bf16.h>
#include <cstddef>

#define N_SAMP 256
#define P_TOK  128
#define EMBED  1024
#define INTER  4096
#define OUT_BASE 672
#define NPAD   768
#define M_TOT  (N_SAMP * P_TOK)   // 32768

typedef __bf16 bf16_t;
typedef bf16_t bf16x8 __attribute__((ext_vector_type(8)));
typedef float  f32x4  __attribute__((ext_vector_type(4)));

// ---------------- conversion kernels ----------------

__global__ void cvt_f32_bf16(const float* __restrict__ in,
                             bf16_t* __restrict__ out, long n4) {
    long i = (long)blockIdx.x * blockDim.x + threadIdx.x;
    if (i >= n4) return;
    float4 v = ((const float4*)in)[i];
    ushort4 o;
    o.x = __builtin_bit_cast(unsigned short, __float2bfloat16(v.x));
    o.y = __builtin_bit_cast(unsigned short, __float2bfloat16(v.y));
    o.z = __builtin_bit_cast(unsigned short, __float2bfloat16(v.z));
    o.w = __builtin_bit_cast(unsigned short, __float2bfloat16(v.w));
    ((ushort4*)out)[i] = o;
}

// convert rows [0,rows_in) and zero-fill rows [rows_in, rows_out) of an
// (rows_out x cols) bf16 buffer from an (rows_in x cols) f32 source.
__global__ void cvt_pad_f32_bf16(const float* __restrict__ in,
                                 bf16_t* __restrict__ out,
                                 int rows_in, int cols, long n4) {
    long i = (long)blockIdx.x * blockDim.x + threadIdx.x;
    if (i >= n4) return;
    long e = i * 4;
    int row = (int)(e / cols);
    int col = (int)(e % cols);
    ushort4 o = {0, 0, 0, 0};
    if (row < rows_in) {
        float4 v = *(const float4*)(in + (size_t)row * cols + col);
        o.x = __builtin_bit_cast(unsigned short, __float2bfloat16(v.x));
        o.y = __builtin_bit_cast(unsigned short, __float2bfloat16(v.y));
        o.z = __builtin_bit_cast(unsigned short, __float2bfloat16(v.z));
        o.w = __builtin_bit_cast(unsigned short, __float2bfloat16(v.w));
    }
    ((ushort4*)out)[i] = o;
}

// ---------------- GEMM (m97 structure) ----------------
// C[M,N] = A[M,K] * B[N,K]^T  (both bf16, fp32 accum)
// 128x128 tile, BK=32, 4 waves (2x2), 16x16x32 bf16 MFMA,
// global_load_lds width-16 staging. M%128==0, N%128==0, K%32==0.

template<int HAS_BIAS, int STORE_BF16>
__global__ __launch_bounds__(256) void gemm_bt(
    const bf16_t* __restrict__ A,
    const bf16_t* __restrict__ B,
    void* __restrict__ Cv,
    const float* __restrict__ bias,
    int M, int N, int K)
{
    __shared__ __align__(16) bf16_t As[128 * 32];
    __shared__ __align__(16) bf16_t Bs[128 * 32];

    const int nTn = N >> 7;
    // XCD-aware bijective swizzle (grid % 8 == 0 for all our launches)
    const int nwg = gridDim.x;
    const int bid = blockIdx.x;
    const int cpx = nwg >> 3;
    const int swz = (bid & 7) * cpx + (bid >> 3);
    const int tm = swz / nTn;
    const int tn = swz % nTn;

    const int t    = threadIdx.x;
    const int lane = t & 63;
    const int wave = t >> 6;
    const int wr   = wave >> 1;   // 0..1
    const int wc   = wave & 1;    // 0..1

    f32x4 acc[4][4];
#pragma unroll
    for (int i = 0; i < 4; ++i)
#pragma unroll
        for (int j = 0; j < 4; ++j) acc[i][j] = (f32x4){0.f, 0.f, 0.f, 0.f};

    const int arow = t >> 2;        // 0..63
    const int acol = (t & 3) * 8;   // 0,8,16,24

    const bf16_t* Abase = A + (size_t)(tm * 128) * K;
    const bf16_t* Bbase = B + (size_t)(tn * 128) * K;

    for (int k0 = 0; k0 < K; k0 += 32) {
#pragma unroll
        for (int j = 0; j < 2; ++j) {
            const bf16_t* ga = Abase + (size_t)(j * 64 + arow) * K + k0 + acol;
            const bf16_t* gb = Bbase + (size_t)(j * 64 + arow) * K + k0 + acol;
            __builtin_amdgcn_global_load_lds(
                (const __attribute__((address_space(1))) void*)ga,
                (__attribute__((address_space(3))) void*)(As + j * 2048 + t * 8),
                16, 0, 0);
            __builtin_amdgcn_global_load_lds(
                (const __attribute__((address_space(1))) void*)gb,
                (__attribute__((address_space(3))) void*)(Bs + j * 2048 + t * 8),
                16, 0, 0);
        }
        __syncthreads();

        bf16x8 af[4], bfr[4];
#pragma unroll
        for (int mi = 0; mi < 4; ++mi)
            af[mi] = *(const bf16x8*)(As + ((wr * 64 + mi * 16 + (lane & 15)) * 32 + (lane >> 4) * 8));
#pragma unroll
        for (int ni = 0; ni < 4; ++ni)
            bfr[ni] = *(const bf16x8*)(Bs + ((wc * 64 + ni * 16 + (lane & 15)) * 32 + (lane >> 4) * 8));
#pragma unroll
        for (int mi = 0; mi < 4; ++mi)
#pragma unroll
            for (int ni = 0; ni < 4; ++ni)
                acc[mi][ni] = __builtin_amdgcn_mfma_f32_16x16x32_bf16(
                    af[mi], bfr[ni], acc[mi][ni], 0, 0, 0);
        __syncthreads();
    }

    const int crow0 = tm * 128 + wr * 64;
    const int ccol0 = tn * 128 + wc * 64;
#pragma unroll
    for (int ni = 0; ni < 4; ++ni) {
        const int col = ccol0 + ni * 16 + (lane & 15);
        const float bv = HAS_BIAS ? bias[col] : 0.f;
#pragma unroll
        for (int mi = 0; mi < 4; ++mi) {
#pragma unroll
            for (int j = 0; j < 4; ++j) {
                const int row = crow0 + mi * 16 + (lane >> 4) * 4 + j;
                float v = acc[mi][ni][j] + bv;
                if (STORE_BF16)
                    ((unsigned short*)Cv)[(size_t)row * N + col] =
                        __builtin_bit_cast(unsigned short, __float2bfloat16(v));
                else
                    ((float*)Cv)[(size_t)row * N + col] = v;
            }
        }
    }
}

// ---------------- epilogue: interp + silu + residual ----------------
// out[m, t] = silu((1-lam)L[i0]+lam*L[i1] + interp(b_sh)) +
//             (1-lam)R[i0]+lam*R[i1] + interp(b_res),  t < T = psize*21, else 0

__global__ __launch_bounds__(256) void epilogue_kernel(
    const float* __restrict__ L, const float* __restrict__ R,
    const float* __restrict__ b_sh, const float* __restrict__ b_res,
    const int* __restrict__ ps, float* __restrict__ out, int maxdim)
{
    const int m = blockIdx.x;            // 0..32767
    const int n = m >> 7;                // sample index
    const int psize = ps[n];
    const int T = psize * 21;
    const float scale = 32.0f / (float)psize;   // 672 / T

    const float* Lr = L + (size_t)m * NPAD;
    const float* Rr = R + (size_t)m * NPAD;
    float* orow = out + (size_t)m * maxdim;

    for (int t = threadIdx.x; t < maxdim; t += 256) {
        float v = 0.f;
        if (t < T) {
            float src = fmaxf(((float)t + 0.5f) * scale - 0.5f, 0.f);
            int i0 = (int)src;                   // floor (src >= 0)
            if (i0 > OUT_BASE - 1) i0 = OUT_BASE - 1;
            int i1 = i0 + 1;
            if (i1 > OUT_BASE - 1) i1 = OUT_BASE - 1;
            float lam = src - (float)i0;
            float a0 = Lr[i0] + b_sh[i0];
            float a1 = Lr[i1] + b_sh[i1];
            float lin = (1.f - lam) * a0 + lam * a1;
            float r0 = Rr[i0] + b_res[i0];
            float r1 = Rr[i1] + b_res[i1];
            float res = (1.f - lam) * r0 + lam * r1;
            float sig = 1.f / (1.f + expf(-lin));
            v = lin * sig + res;
        }
        orow[t] = v;
    }
}

// ---------------- launch ----------------

extern "C" void kernel_launch(void* const* d_in, const int* in_sizes, int n_in,
                              void* d_out, int out_size, void* d_ws, size_t ws_size,
                              hipStream_t stream) {
    const float* x     = (const float*)d_in[0];
    const int*   ps    = (const int*)d_in[1];
    const float* W_in  = (const float*)d_in[2];
    const float* b_in  = (const float*)d_in[3];
    const float* W_sh  = (const float*)d_in[4];
    const float* b_sh  = (const float*)d_in[5];
    const float* W_res = (const float*)d_in[6];
    const float* b_res = (const float*)d_in[7];
    float* out = (float*)d_out;

    const int maxdim = out_size / M_TOT;   // 1344 for this data

    // workspace layout
    size_t need = 0;
    char* w = (char*)d_ws;
    bf16_t* x_b    = (bf16_t*)(w + need); need += (size_t)M_TOT * EMBED * 2;   //  67.1 MB
    bf16_t* Win_b  = (bf16_t*)(w + need); need += (size_t)INTER * EMBED * 2;   //   8.4 MB
    bf16_t* Wsh_b  = (bf16_t*)(w + need); need += (size_t)NPAD * INTER * 2;    //   6.3 MB
    bf16_t* Wres_b = (bf16_t*)(w + need); need += (size_t)NPAD * EMBED * 2;    //   1.6 MB
    bf16_t* xs_b   = (bf16_t*)(w + need); need += (size_t)M_TOT * INTER * 2;   // 268.4 MB
    float*  Lbuf   = (float*)(w + need);  need += (size_t)M_TOT * NPAD * 4;    // 100.7 MB
    float*  Rbuf   = (float*)(w + need);  need += (size_t)M_TOT * NPAD * 4;    // 100.7 MB
    if (ws_size < need) return;  // fail loudly (poisoned output) if ws too small

    // conversions to bf16
    {
        long n4 = (long)M_TOT * EMBED / 4;
        cvt_f32_bf16<<<(int)((n4 + 255) / 256), 256, 0, stream>>>(x, x_b, n4);
        n4 = (long)INTER * EMBED / 4;
        cvt_f32_bf16<<<(int)((n4 + 255) / 256), 256, 0, stream>>>(W_in, Win_b, n4);
        n4 = (long)NPAD * INTER / 4;
        cvt_pad_f32_bf16<<<(int)((n4 + 255) / 256), 256, 0, stream>>>(W_sh, Wsh_b, OUT_BASE, INTER, n4);
        n4 = (long)NPAD * EMBED / 4;
        cvt_pad_f32_bf16<<<(int)((n4 + 255) / 256), 256, 0, stream>>>(W_res, Wres_b, OUT_BASE, EMBED, n4);
    }

    // GEMM1: xs = x @ W_in^T + b_in   (store bf16)
    gemm_bt<1, 1><<<(M_TOT / 128) * (INTER / 128), 256, 0, stream>>>(
        x_b, Win_b, xs_b, b_in, M_TOT, INTER, EMBED);

    // GEMM2: L = xs @ W_shared^T   (f32 out, padded N)
    gemm_bt<0, 0><<<(M_TOT / 128) * (NPAD / 128), 256, 0, stream>>>(
        xs_b, Wsh_b, Lbuf, nullptr, M_TOT, NPAD, INTER);

    // GEMM3: R = x @ W_res^T
    gemm_bt<0, 0><<<(M_TOT / 128) * (NPAD / 128), 256, 0, stream>>>(
        x_b, Wres_b, Rbuf, nullptr, M_TOT, NPAD, EMBED);

    // epilogue: interpolate + silu + residual + zero-pad
    epilogue_kernel<<<M_TOT, 256, 0, stream>>>(Lbuf, Rbuf, b_sh, b_res, ps, out, maxdim);
}

// Round 4
// 964.139 us; speedup vs baseline: 1.2754x; 1.2754x over previous
//
#include <hip/hip_runtime.h>
#include <hip/hip_bf16.h>
#include <cstddef>

#define EMBED  1024
#define INTER  4096
#define OUT_BASE 672
#define NPAD   768
#define M_TOT  32768

typedef __bf16 bf16_t;
typedef bf16_t bf16x8 __attribute__((ext_vector_type(8)));
typedef float  f32x4  __attribute__((ext_vector_type(4)));

// ---------------- conversion kernels ----------------

__global__ void cvt_f32_bf16(const float* __restrict__ in,
                             bf16_t* __restrict__ out, long n4) {
    long i = (long)blockIdx.x * blockDim.x + threadIdx.x;
    if (i >= n4) return;
    float4 v = ((const float4*)in)[i];
    ushort4 o;
    o.x = __builtin_bit_cast(unsigned short, __float2bfloat16(v.x));
    o.y = __builtin_bit_cast(unsigned short, __float2bfloat16(v.y));
    o.z = __builtin_bit_cast(unsigned short, __float2bfloat16(v.z));
    o.w = __builtin_bit_cast(unsigned short, __float2bfloat16(v.w));
    ((ushort4*)out)[i] = o;
}

__global__ void cvt_pad_f32_bf16(const float* __restrict__ in,
                                 bf16_t* __restrict__ out,
                                 int rows_in, int cols, long n4) {
    long i = (long)blockIdx.x * blockDim.x + threadIdx.x;
    if (i >= n4) return;
    long e = i * 4;
    int row = (int)(e / cols);
    int col = (int)(e % cols);
    ushort4 o = {0, 0, 0, 0};
    if (row < rows_in) {
        float4 v = *(const float4*)(in + (size_t)row * cols + col);
        o.x = __builtin_bit_cast(unsigned short, __float2bfloat16(v.x));
        o.y = __builtin_bit_cast(unsigned short, __float2bfloat16(v.y));
        o.z = __builtin_bit_cast(unsigned short, __float2bfloat16(v.z));
        o.w = __builtin_bit_cast(unsigned short, __float2bfloat16(v.w));
    }
    ((ushort4*)out)[i] = o;
}

// ---------------- pipelined GEMM ----------------
// C[M,N] = A[M,K] * B[N,K]^T  (bf16 in, fp32 accum, bf16 out)
// BN=256, BK=32, 512 threads = 8 waves (2 Mwaves x 4 Nwaves).
// 4 LDS buffers, 3-tiles-ahead prefetch via global_load_lds,
// counted vmcnt (T4), 2-phase MFMA interleave (T3), setprio (T5),
// XOR LDS swizzle via pre-swizzled global source (T2 + rule #21).
// Swizzle: element_off = row*32 + ((colblk ^ ((row>>1)&3))<<3).
// Requires: M%BM==0, N%256==0 for launch tiling, K%32==0, K/32 >= 3.

template<int BM, int HAS_BIAS>
__global__ __launch_bounds__(512, 2) void gemm3p(
    const bf16_t* __restrict__ A,
    const bf16_t* __restrict__ B,
    bf16_t* __restrict__ C,
    const float* __restrict__ bias,
    int M, int N, int K)
{
    constexpr int MF   = BM / 32;          // M-frags per wave (4 or 8)
    constexpr int A_LD = (BM * 4) / 512;   // A chunk-loads per thread (1 or 2)
    constexpr int L_ISS = A_LD + 2;        // loads/thread/tile
    constexpr int AE   = BM * 32;          // A tile elements
    constexpr int BUFE = AE + 8192;        // elements per buffer (A + B[256x32])

    __shared__ __align__(16) bf16_t lds[4 * BUFE];

    // XCD-aware swizzle (grids are multiples of 8)
    const int nwg = gridDim.x;
    const int bid = blockIdx.x;
    const int cpx = nwg >> 3;
    const int swz = (bid & 7) * cpx + (bid >> 3);
    const int nTn = N >> 8;
    const int tm = swz / nTn;
    const int tn = swz % nTn;
    const int tmBM  = tm * BM;
    const int tn256 = tn * 256;

    const int tid  = threadIdx.x;
    const int lane = tid & 63;
    const int wave = tid >> 6;
    const int wr   = wave >> 2;   // 0..1
    const int wc   = wave & 3;    // 0..3

    f32x4 acc[MF][4];
#pragma unroll
    for (int m = 0; m < MF; ++m)
#pragma unroll
        for (int n = 0; n < 4; ++n) acc[m][n] = (f32x4){0.f, 0.f, 0.f, 0.f};

    // per-thread swizzled LDS read offsets (elements)
    int a_off[MF], b_off[4];
#pragma unroll
    for (int m = 0; m < MF; ++m) {
        const int r = wr * (BM / 2) + m * 16 + (lane & 15);
        a_off[m] = r * 32 + ((((lane >> 4) ^ ((r >> 1) & 3))) << 3);
    }
#pragma unroll
    for (int n = 0; n < 4; ++n) {
        const int r = wc * 64 + n * 16 + (lane & 15);
        b_off[n] = r * 32 + ((((lane >> 4) ^ ((r >> 1) & 3))) << 3);
    }

    const int NT = K >> 5;

    // ---- prologue: stage tiles 0,1,2 into buffers 0,1,2 ----
    for (int pt = 0; pt < 3; ++pt) {
        const int k0 = pt << 5;
        bf16_t* Abp = lds + pt * BUFE;
        bf16_t* Bbp = Abp + AE;
#pragma unroll
        for (int l = 0; l < A_LD; ++l) {
            const int c = tid + (l << 9);
            const int r = c >> 2;
            const bf16_t* g = A + (size_t)(tmBM + r) * K + k0 +
                              (((c & 3) ^ ((r >> 1) & 3)) << 3);
            __builtin_amdgcn_global_load_lds(
                (const __attribute__((address_space(1))) void*)g,
                (__attribute__((address_space(3))) void*)(Abp + c * 8), 16, 0, 0);
        }
#pragma unroll
        for (int l = 0; l < 2; ++l) {
            const int c = tid + (l << 9);
            const int r = c >> 2;
            const bf16_t* g = B + (size_t)(tn256 + r) * K + k0 +
                              (((c & 3) ^ ((r >> 1) & 3)) << 3);
            __builtin_amdgcn_global_load_lds(
                (const __attribute__((address_space(1))) void*)g,
                (__attribute__((address_space(3))) void*)(Bbp + c * 8), 16, 0, 0);
        }
    }

    int bufc = 0;
    for (int t = 0; t < NT; ++t) {
        // wait: tile t fully landed (tiles t+1, t+2 may remain in flight)
        const int ahead = NT - 1 - t;
        if constexpr (L_ISS == 4) {
            if (ahead >= 2)      asm volatile("s_waitcnt vmcnt(8)\n\ts_barrier" ::: "memory");
            else if (ahead == 1) asm volatile("s_waitcnt vmcnt(4)\n\ts_barrier" ::: "memory");
            else                 asm volatile("s_waitcnt vmcnt(0)\n\ts_barrier" ::: "memory");
        } else {
            if (ahead >= 2)      asm volatile("s_waitcnt vmcnt(6)\n\ts_barrier" ::: "memory");
            else if (ahead == 1) asm volatile("s_waitcnt vmcnt(3)\n\ts_barrier" ::: "memory");
            else                 asm volatile("s_waitcnt vmcnt(0)\n\ts_barrier" ::: "memory");
        }

        bf16_t* Ab = lds + bufc * BUFE;
        bf16_t* Bb = Ab + AE;
        const int tpre = t + 3;
        const int bpre = tpre & 3;

        // ---- phase A: read A-frags + B-frags 0,1; stage A of tile t+3 ----
        bf16x8 af[MF];
#pragma unroll
        for (int m = 0; m < MF; ++m) af[m] = *(const bf16x8*)(Ab + a_off[m]);
        bf16x8 bfr0 = *(const bf16x8*)(Bb + b_off[0]);
        bf16x8 bfr1 = *(const bf16x8*)(Bb + b_off[1]);

        if (tpre < NT) {
            const int k0 = tpre << 5;
            bf16_t* Abp = lds + bpre * BUFE;
#pragma unroll
            for (int l = 0; l < A_LD; ++l) {
                const int c = tid + (l << 9);
                const int r = c >> 2;
                const bf16_t* g = A + (size_t)(tmBM + r) * K + k0 +
                                  (((c & 3) ^ ((r >> 1) & 3)) << 3);
                __builtin_amdgcn_global_load_lds(
                    (const __attribute__((address_space(1))) void*)g,
                    (__attribute__((address_space(3))) void*)(Abp + c * 8), 16, 0, 0);
            }
        }

        __builtin_amdgcn_s_setprio(1);
#pragma unroll
        for (int m = 0; m < MF; ++m)
            acc[m][0] = __builtin_amdgcn_mfma_f32_16x16x32_bf16(af[m], bfr0, acc[m][0], 0, 0, 0);
#pragma unroll
        for (int m = 0; m < MF; ++m)
            acc[m][1] = __builtin_amdgcn_mfma_f32_16x16x32_bf16(af[m], bfr1, acc[m][1], 0, 0, 0);
        __builtin_amdgcn_s_setprio(0);

        // ---- phase B: read B-frags 2,3; stage B of tile t+3 ----
        bf16x8 bfr2 = *(const bf16x8*)(Bb + b_off[2]);
        bf16x8 bfr3 = *(const bf16x8*)(Bb + b_off[3]);

        if (tpre < NT) {
            const int k0 = tpre << 5;
            bf16_t* Bbp = lds + bpre * BUFE + AE;
#pragma unroll
            for (int l = 0; l < 2; ++l) {
                const int c = tid + (l << 9);
                const int r = c >> 2;
                const bf16_t* g = B + (size_t)(tn256 + r) * K + k0 +
                                  (((c & 3) ^ ((r >> 1) & 3)) << 3);
                __builtin_amdgcn_global_load_lds(
                    (const __attribute__((address_space(1))) void*)g,
                    (__attribute__((address_space(3))) void*)(Bbp + c * 8), 16, 0, 0);
            }
        }

        __builtin_amdgcn_s_setprio(1);
#pragma unroll
        for (int m = 0; m < MF; ++m)
            acc[m][2] = __builtin_amdgcn_mfma_f32_16x16x32_bf16(af[m], bfr2, acc[m][2], 0, 0, 0);
#pragma unroll
        for (int m = 0; m < MF; ++m)
            acc[m][3] = __builtin_amdgcn_mfma_f32_16x16x32_bf16(af[m], bfr3, acc[m][3], 0, 0, 0);
        __builtin_amdgcn_s_setprio(0);

        bufc = (bufc + 1) & 3;
    }

    // ---- epilogue: C-write (bf16), verified fragment layout ----
    const int crow0 = tmBM + wr * (BM / 2);
    const int ccol0 = tn256 + wc * 64;
#pragma unroll
    for (int n = 0; n < 4; ++n) {
        const int col = ccol0 + n * 16 + (lane & 15);
        const float bv = HAS_BIAS ? bias[col] : 0.f;
#pragma unroll
        for (int m = 0; m < MF; ++m) {
#pragma unroll
            for (int j = 0; j < 4; ++j) {
                const int row = crow0 + m * 16 + (lane >> 4) * 4 + j;
                float v = acc[m][n][j] + bv;
                ((unsigned short*)C)[(size_t)row * N + col] =
                    __builtin_bit_cast(unsigned short, __float2bfloat16(v));
            }
        }
    }
}

// ---------------- epilogue: interp + silu + residual ----------------

__global__ __launch_bounds__(256) void epilogue_kernel(
    const bf16_t* __restrict__ L, const bf16_t* __restrict__ R,
    const float* __restrict__ b_sh, const float* __restrict__ b_res,
    const int* __restrict__ ps, float* __restrict__ out, int maxdim)
{
    const int m = blockIdx.x;            // 0..32767
    const int n = m >> 7;                // sample index
    const int psize = ps[n];
    const int T = psize * 21;
    const float scale = 32.0f / (float)psize;   // 672 / T

    const bf16_t* Lr = L + (size_t)m * NPAD;
    const bf16_t* Rr = R + (size_t)m * NPAD;
    float* orow = out + (size_t)m * maxdim;

    for (int t = threadIdx.x; t < maxdim; t += 256) {
        float v = 0.f;
        if (t < T) {
            float src = fmaxf(((float)t + 0.5f) * scale - 0.5f, 0.f);
            int i0 = (int)src;
            if (i0 > OUT_BASE - 1) i0 = OUT_BASE - 1;
            int i1 = i0 + 1;
            if (i1 > OUT_BASE - 1) i1 = OUT_BASE - 1;
            float lam = src - (float)i0;
            float a0 = (float)Lr[i0] + b_sh[i0];
            float a1 = (float)Lr[i1] + b_sh[i1];
            float lin = (1.f - lam) * a0 + lam * a1;
            float r0 = (float)Rr[i0] + b_res[i0];
            float r1 = (float)Rr[i1] + b_res[i1];
            float res = (1.f - lam) * r0 + lam * r1;
            float sig = 1.f / (1.f + expf(-lin));
            v = lin * sig + res;
        }
        orow[t] = v;
    }
}

// ---------------- launch ----------------

extern "C" void kernel_launch(void* const* d_in, const int* in_sizes, int n_in,
                              void* d_out, int out_size, void* d_ws, size_t ws_size,
                              hipStream_t stream) {
    const float* x     = (const float*)d_in[0];
    const int*   ps    = (const int*)d_in[1];
    const float* W_in  = (const float*)d_in[2];
    const float* b_in  = (const float*)d_in[3];
    const float* W_sh  = (const float*)d_in[4];
    const float* b_sh  = (const float*)d_in[5];
    const float* W_res = (const float*)d_in[6];
    const float* b_res = (const float*)d_in[7];
    float* out = (float*)d_out;

    const int maxdim = out_size / M_TOT;   // 1344

    // workspace layout (all offsets 16B-aligned)
    size_t need = 0;
    char* w = (char*)d_ws;
    bf16_t* x_b    = (bf16_t*)(w + need); need += (size_t)M_TOT * EMBED * 2;   //  67.1 MB
    bf16_t* Win_b  = (bf16_t*)(w + need); need += (size_t)INTER * EMBED * 2;   //   8.4 MB
    bf16_t* Wsh_b  = (bf16_t*)(w + need); need += (size_t)NPAD * INTER * 2;    //   6.3 MB
    bf16_t* Wres_b = (bf16_t*)(w + need); need += (size_t)NPAD * EMBED * 2;    //   1.6 MB
    bf16_t* xs_b   = (bf16_t*)(w + need); need += (size_t)M_TOT * INTER * 2;   // 268.4 MB
    bf16_t* Lbuf   = (bf16_t*)(w + need); need += (size_t)M_TOT * NPAD * 2;    //  50.3 MB
    bf16_t* Rbuf   = (bf16_t*)(w + need); need += (size_t)M_TOT * NPAD * 2;    //  50.3 MB
    if (ws_size < need) return;

    // conversions to bf16
    {
        long n4 = (long)M_TOT * EMBED / 4;
        cvt_f32_bf16<<<(int)((n4 + 255) / 256), 256, 0, stream>>>(x, x_b, n4);
        n4 = (long)INTER * EMBED / 4;
        cvt_f32_bf16<<<(int)((n4 + 255) / 256), 256, 0, stream>>>(W_in, Win_b, n4);
        n4 = (long)NPAD * INTER / 4;
        cvt_pad_f32_bf16<<<(int)((n4 + 255) / 256), 256, 0, stream>>>(W_sh, Wsh_b, OUT_BASE, INTER, n4);
        n4 = (long)NPAD * EMBED / 4;
        cvt_pad_f32_bf16<<<(int)((n4 + 255) / 256), 256, 0, stream>>>(W_res, Wres_b, OUT_BASE, EMBED, n4);
    }

    // GEMM1: xs = x @ W_in^T + b_in      BM=256: grid 128x16 = 2048 blocks
    gemm3p<256, 1><<<(M_TOT / 256) * (INTER / 256), 512, 0, stream>>>(
        x_b, Win_b, xs_b, b_in, M_TOT, INTER, EMBED);

    // GEMM2: L = xs @ W_shared^T         BM=128: grid 256x3 = 768 blocks
    gemm3p<128, 0><<<(M_TOT / 128) * (NPAD / 256), 512, 0, stream>>>(
        xs_b, Wsh_b, Lbuf, nullptr, M_TOT, NPAD, INTER);

    // GEMM3: R = x @ W_res^T
    gemm3p<128, 0><<<(M_TOT / 128) * (NPAD / 256), 512, 0, stream>>>(
        x_b, Wres_b, Rbuf, nullptr, M_TOT, NPAD, EMBED);

    // epilogue: interpolate + silu + residual + zero-pad
    epilogue_kernel<<<M_TOT, 256, 0, stream>>>(Lbuf, Rbuf, b_sh, b_res, ps, out, maxdim);
}